// Round 1
// 369.234 us; speedup vs baseline: 1.2059x; 1.2059x over previous
//
#include <hip/hip_runtime.h>
#include <hip/hip_bf16.h>
#include <stdint.h>

// Problem: B=16, S=2048, H=1024, A=8 — all tensors FLOAT32 (per reference).
//   scores[b,s] = sum_n tanh( token[b,s,:]@W_top[:,n] + c[b,n] ) * v[n]
//   c[b,n] = mean_a(aspect[b,a,:]) @ W_bot[:,n] + bias[n]
//   out = token * (1 + softmax_S(scores))
// GEMM runs in bf16 MFMA (fp32 accum); token and W_top are pre-converted to
// bf16 scratch living in d_out (dead until the final scale_k overwrites it).
// No atomics, no zero-init anywhere (partial layouts) — no dependence on
// memset/poison semantics.

#define SEQ 2048
#define H 1024
#define MTOT 32768   // B*S
#define BK 32

typedef __bf16 bf16x8 __attribute__((ext_vector_type(8)));
typedef float  f32x4  __attribute__((ext_vector_type(4)));

__device__ __forceinline__ void async16(const void* g, void* l) {
  __builtin_amdgcn_global_load_lds(
      (const __attribute__((address_space(1))) unsigned*)g,
      (__attribute__((address_space(3))) unsigned*)l, 16, 0, 0);
}

__device__ __forceinline__ unsigned f2bfraw(float f) {
  unsigned x = __float_as_uint(f);
  return (x + 0x7fffu + ((x >> 16) & 1u)) >> 16;   // RN-even, finite inputs
}
__device__ __forceinline__ float fast_tanh(float x) {
  x = fminf(fmaxf(x, -40.0f), 40.0f);
  float e = __expf(2.0f * x);
  return 1.0f - 2.0f / (e + 1.0f);
}

// ---- token f32 -> bf16 (into d_out head scratch) -------------------------
__global__ __launch_bounds__(256) void convert_tok(
    const float* __restrict__ in, unsigned short* __restrict__ ob) {
  const size_t i = ((size_t)blockIdx.x * 256 + threadIdx.x) * 8;
  const f32x4 a = *reinterpret_cast<const f32x4*>(in + i);
  const f32x4 b = *reinterpret_cast<const f32x4*>(in + i + 4);
  uint4 r;
  r.x = f2bfraw(a[0]) | (f2bfraw(a[1]) << 16);
  r.y = f2bfraw(a[2]) | (f2bfraw(a[3]) << 16);
  r.z = f2bfraw(b[0]) | (f2bfraw(b[1]) << 16);
  r.w = f2bfraw(b[2]) | (f2bfraw(b[3]) << 16);
  *reinterpret_cast<uint4*>(ob + i) = r;
}

// ---- W_top transpose+convert: WT[n][k] = bf16(W[k][n]), k<1024 ----------
__global__ __launch_bounds__(256) void transpose_w(
    const float* __restrict__ W, unsigned short* __restrict__ WT) {
  __shared__ float tile[32][33];
  const int x = threadIdx.x;        // 0..31
  const int y = threadIdx.y;        // 0..7
  const int n0 = blockIdx.x * 32, k0 = blockIdx.y * 32;
#pragma unroll
  for (int i = 0; i < 4; ++i)
    tile[y + 8 * i][x] = W[(size_t)(k0 + y + 8 * i) * H + n0 + x];
  __syncthreads();
#pragma unroll
  for (int i = 0; i < 4; ++i)
    WT[(size_t)(n0 + y + 8 * i) * H + k0 + x] = (unsigned short)f2bfraw(tile[x][y + 8 * i]);
}

// ---- cpart[kc][b][n]: k-split partials of mean_a(aspect)@W_bot (+bias) --
// grid (16 b, 4 nc, 4 kc) = 256 blocks, 256 thr = 4 waves (k-sub) x 64
// lanes (float4 over n). No atomics: gemm epilogue sums the 4 kc partials.
__global__ __launch_bounds__(256) void aspect_c(
    const float* __restrict__ asp,   // [16][8][1024]
    const float* __restrict__ W,     // [2048][1024]
    const float* __restrict__ bias,  // [1024]
    float* __restrict__ cpart) {     // [4][16][1024]
  const int b = blockIdx.x, nc = blockIdx.y, kc = blockIdx.z;
  const int t = threadIdx.x;
  const int lane = t & 63, w = t >> 6;
  __shared__ float am[256];
  __shared__ f32x4 red[4][64];
  {
    const int k = kc * 256 + t;
    float s = 0.f;
#pragma unroll
    for (int a = 0; a < 8; ++a) s += asp[(size_t)(b * 8 + a) * H + k];
    am[t] = s * 0.125f;
  }
  __syncthreads();
  const int n = nc * 256 + lane * 4;
  const float* wp = W + (size_t)(H + kc * 256 + w * 64) * H + n;
  f32x4 acc = {};
#pragma unroll 8
  for (int k = 0; k < 64; ++k) {
    const f32x4 wv = *reinterpret_cast<const f32x4*>(wp + (size_t)k * H);
    const float a = am[w * 64 + k];
    acc[0] += a * wv[0]; acc[1] += a * wv[1];
    acc[2] += a * wv[2]; acc[3] += a * wv[3];
  }
  red[w][lane] = acc;
  __syncthreads();
  if (w == 0) {
    f32x4 r = red[0][lane];
#pragma unroll
    for (int i = 1; i < 4; ++i) {
      const f32x4 x = red[i][lane];
      r[0] += x[0]; r[1] += x[1]; r[2] += x[2]; r[3] += x[3];
    }
    if (kc == 0) {
      r[0] += bias[n];     r[1] += bias[n + 1];
      r[2] += bias[n + 2]; r[3] += bias[n + 3];
    }
    *reinterpret_cast<f32x4*>(cpart + (size_t)kc * 16 * H + b * H + n) = r;
  }
}

// ---- main GEMM (bf16 MFMA) + tanh*v row-reduce -> partial scores --------
// grid (8 n-blocks, 256 m-blocks), 256 thr (4 waves, 2x2 of 64x64 tiles).
// XCD-aware bijective swizzle: nwg=2048 = 8*256; xcd = bid%8 gets a
// contiguous 32-m-strip chunk with n fastest -> A-panel (256 KB) reused
// from that XCD's L2 across its 8 consecutive n-blocks.
__global__ __launch_bounds__(256) void gemm_score(
    const __hip_bfloat16* __restrict__ tokb,  // [32768][1024] bf16
    const __hip_bfloat16* __restrict__ wt,    // WT [1024 n][1024 k] bf16
    const float* __restrict__ cpart,          // [4][16][1024] (kc0 has bias)
    const float* __restrict__ v,              // [1024] f32
    float* __restrict__ part) {               // [16][32768] partial scores
  __shared__ __hip_bfloat16 As[128 * BK];     // 8 KB  [m][k]
  __shared__ __hip_bfloat16 Bs[128 * BK];     // 8 KB  [n][k]
  const int t = threadIdx.x;
  const int lane = t & 63;
  const int w = t >> 6;
  const int wm = w >> 1, wn = w & 1;
  const unsigned bidl = blockIdx.x + (blockIdx.y << 3);       // hw linear id
  const unsigned nb = ((bidl & 7u) << 8) | (bidl >> 3);       // bijective
  const int bx = nb & 7;             // n-block
  const int by = nb >> 3;            // m-block
  const int m0 = by * 128;
  const int n0 = bx * 128;
  const int bb = by >> 4;            // 16 M-blocks per batch

  f32x4 acc[4][4] = {};

  const int srow = t >> 2, scol = (t & 3) * 8;
  const __hip_bfloat16* ga = tokb + (size_t)(m0 + srow) * H + scol;
  const __hip_bfloat16* gb = wt + (size_t)(n0 + srow) * H + scol;
  __hip_bfloat16* la0 = As + t * 8;
  __hip_bfloat16* la1 = As + t * 8 + 64 * BK;
  __hip_bfloat16* lb0 = Bs + t * 8;
  __hip_bfloat16* lb1 = Bs + t * 8 + 64 * BK;

  const int quad = lane >> 4, l16 = lane & 15;

  for (int k0 = 0; k0 < H; k0 += BK) {
    __syncthreads();
    async16(ga + k0, la0);
    async16(ga + k0 + (size_t)64 * H, la1);
    async16(gb + k0, lb0);
    async16(gb + k0 + (size_t)64 * H, lb1);
    __syncthreads();

    bf16x8 af[4], bf[4];
#pragma unroll
    for (int mi = 0; mi < 4; ++mi)
      af[mi] = *reinterpret_cast<const bf16x8*>(
          As + (wm * 64 + mi * 16 + l16) * BK + quad * 8);
#pragma unroll
    for (int ni = 0; ni < 4; ++ni)
      bf[ni] = *reinterpret_cast<const bf16x8*>(
          Bs + (wn * 64 + ni * 16 + l16) * BK + quad * 8);
#pragma unroll
    for (int mi = 0; mi < 4; ++mi)
#pragma unroll
      for (int ni = 0; ni < 4; ++ni)
        acc[mi][ni] = __builtin_amdgcn_mfma_f32_16x16x32_bf16(
            af[mi], bf[ni], acc[mi][ni], 0, 0, 0);
  }

  // epilogue: partial_score_row = sum_n tanh(acc + c[b][n]) * v[n]
  float vv[4], cc[4];
#pragma unroll
  for (int ni = 0; ni < 4; ++ni) {
    const int gn = n0 + wn * 64 + ni * 16 + l16;
    vv[ni] = v[gn];
    float s = cpart[(size_t)bb * H + gn];                 // kc=0 (has bias)
    s += cpart[(size_t)1 * 16 * H + bb * H + gn];
    s += cpart[(size_t)2 * 16 * H + bb * H + gn];
    s += cpart[(size_t)3 * 16 * H + bb * H + gn];
    cc[ni] = s;
  }
  const size_t pbase = ((size_t)bx * 2 + wn) * MTOT + m0;
#pragma unroll
  for (int mi = 0; mi < 4; ++mi) {
#pragma unroll
    for (int r = 0; r < 4; ++r) {
      float s = 0.f;
#pragma unroll
      for (int ni = 0; ni < 4; ++ni)
        s += fast_tanh(acc[mi][ni][r] + cc[ni]) * vv[ni];
#pragma unroll
      for (int msk = 1; msk < 16; msk <<= 1) s += __shfl_xor(s, msk, 64);
      if (l16 == 0)
        part[pbase + wm * 64 + mi * 16 + quad * 4 + r] = s;  // unique writer
    }
  }
}

// ---- softmax over S per batch (sums 16 partials), 1 block/batch ---------
// 1024 thr (16 waves), scores held in registers: one global pass, one exp.
__global__ __launch_bounds__(1024) void softmax_k(
    const float* __restrict__ part, float* __restrict__ wts) {
  const int b = blockIdx.x, t = threadIdx.x;
  const int lane = t & 63, w = t >> 6;     // 16 waves
  __shared__ float red[16];
  const int s0 = t * 2;
  float sx = 0.f, sy = 0.f;
#pragma unroll
  for (int p = 0; p < 16; ++p) {
    const float2 x = *reinterpret_cast<const float2*>(
        part + (size_t)p * MTOT + b * SEQ + s0);
    sx += x.x; sy += x.y;
  }
  float m = fmaxf(sx, sy);
#pragma unroll
  for (int o = 1; o < 64; o <<= 1) m = fmaxf(m, __shfl_xor(m, o, 64));
  if (lane == 0) red[w] = m;
  __syncthreads();
  m = red[0];
#pragma unroll
  for (int i = 1; i < 16; ++i) m = fmaxf(m, red[i]);
  __syncthreads();
  const float e0 = __expf(sx - m), e1 = __expf(sy - m);
  float sum = e0 + e1;
#pragma unroll
  for (int o = 1; o < 64; o <<= 1) sum += __shfl_xor(sum, o, 64);
  if (lane == 0) red[w] = sum;
  __syncthreads();
  sum = 0.f;
#pragma unroll
  for (int i = 0; i < 16; ++i) sum += red[i];
  const float inv = 1.0f / sum;
  float2 o2; o2.x = e0 * inv; o2.y = e1 * inv;
  *reinterpret_cast<float2*>(wts + (size_t)b * SEQ + s0) = o2;
}

// ---- out = token * (1 + weights) ----------------------------------------
__global__ __launch_bounds__(256) void scale_k(
    const float* __restrict__ tok, const float* __restrict__ wts,
    float* __restrict__ out) {
  const size_t i = ((size_t)blockIdx.x * 256 + threadIdx.x) * 4;
  const float wm = 1.0f + wts[i >> 10];          // 4 elems share a row
  const f32x4 a = *reinterpret_cast<const f32x4*>(tok + i);
  f32x4 o;
  o[0] = a[0] * wm; o[1] = a[1] * wm; o[2] = a[2] * wm; o[3] = a[3] * wm;
  *reinterpret_cast<f32x4*>(out + i) = o;
}

extern "C" void kernel_launch(void* const* d_in, const int* in_sizes, int n_in,
                              void* d_out, int out_size, void* d_ws, size_t ws_size,
                              hipStream_t stream) {
  const float* tok  = (const float*)d_in[0];
  const float* asp  = (const float*)d_in[1];
  const float* W    = (const float*)d_in[2];
  const float* bias = (const float*)d_in[3];
  const float* v    = (const float*)d_in[4];
  float* out = (float*)d_out;

  // Scratch layout inside d_out (33,554,432 f32 total), all dead by scale_k:
  //   [0 .. 16,777,216)          tok_bf16 (33.5M bf16, read by gemm only)
  //   [16,777,216 .. 16,842,752) cpart   (4 x 16 x 1024 f32)
  //   [32,505,856 .. 33,030,144) part    (16 x 32768 f32 partial scores)
  //   [33,030,144 .. 33,554,432) WT      (1M bf16)
  unsigned short* tokb_u = (unsigned short*)out;
  float*          cpart  = out + 16777216;
  float*          part   = out + 32505856;
  unsigned short* WT_u   = (unsigned short*)(out + 33030144);
  // weights must NOT alias d_out (scale_k reads it while writing out):
  // prefer d_ws; else the aspect input buffer (524KB, dead after aspect_c).
  float* wts = (ws_size >= (size_t)(SEQ * 16 * 4)) ? (float*)d_ws
                                                   : (float*)d_in[1];

  convert_tok<<<16384, 256, 0, stream>>>(tok, tokb_u);
  transpose_w<<<dim3(32, 32), dim3(32, 8), 0, stream>>>(W, WT_u);
  aspect_c<<<dim3(16, 4, 4), 256, 0, stream>>>(asp, W, bias, cpart);
  gemm_score<<<dim3(8, 256), 256, 0, stream>>>(
      (const __hip_bfloat16*)tokb_u, (const __hip_bfloat16*)WT_u,
      cpart, v, part);
  softmax_k<<<16, 1024, 0, stream>>>(part, wts);
  scale_k<<<32768, 256, 0, stream>>>(tok, wts, out);
}